// Round 12
// baseline (264.410 us; speedup 1.0000x reference)
//
#include <hip/hip_runtime.h>
#include <math.h>

constexpr int Bn  = 2;
constexpr int Cn  = 128;
constexpr int Hn  = 96;
constexpr int Wn  = 96;
constexpr int HWn = Hn * Wn;        // 9216
constexpr int CHWn = Cn * HWn;      // 1179648
constexpr int KCn = Cn * 9;         // 1152
constexpr float EPSn = 1e-5f;
constexpr int KPAD = 1160;          // LDS row stride in shorts (2320B, 16B-aligned)

typedef short bf16x8 __attribute__((ext_vector_type(8)));
typedef float f32x4  __attribute__((ext_vector_type(4)));

#define SB() __builtin_amdgcn_sched_barrier(0)

static __device__ inline short f2bf(float f) {
    union { float f; unsigned u; } v; v.f = f;
    unsigned r = v.u + 0x7fff + ((v.u >> 16) & 1);
    return (short)(r >> 16);
}
// packed bf16 convert: lo = bf16(a), hi = bf16(b)
static __device__ inline unsigned pack2(float a, float b) {
    unsigned r;
    asm("v_cvt_pk_bf16_f32 %0, %1, %2" : "=v"(r) : "v"(a), "v"(b));
    return r;
}

// k-major permuted weights: wb[o][k*128 + c] = w[o][c*9 + k]
__global__ __launch_bounds__(256) void cvt_w_kernel(
    const float* __restrict__ w, short* __restrict__ wb)
{
    int t = blockIdx.x * 256 + threadIdx.x;   // 128*1152
    if (t >= Cn * KCn) return;
    int o = t / KCn, r = t % KCn;
    int k = r >> 7, c = r & 127;
    wb[t] = f2bf(w[o * KCn + c * 9 + k]);
}

__global__ __launch_bounds__(256) void cvt_ow_kernel(
    const float* __restrict__ ow, short* __restrict__ owb)
{
    int t = blockIdx.x * 256 + threadIdx.x;   // 32*1152
    if (t >= 32 * KCn) return;
    int row = t / KCn, r = t % KCn;
    int k = r >> 7, c = r & 127;
    owb[t] = (row < 27) ? f2bf(ow[row * KCn + c * 9 + k]) : (short)0;
}

// NCHW -> NHWC (global-pixel-major)
__global__ __launch_bounds__(256) void nchw2nhwc(
    const float* __restrict__ x, float* __restrict__ xT)
{
    __shared__ float Tl[128][65];
    const int t = threadIdx.x;
    const int pix0 = blockIdx.x * 64;
    const int b   = pix0 / HWn;
    const int sp0 = pix0 - b * HWn;
    const float* xb = x + b * CHWn + sp0 + (t & 63);
    const int c0 = t >> 6;
#pragma unroll 8
    for (int i = 0; i < 32; ++i) {
        const int c = c0 + 4 * i;
        Tl[c][t & 63] = xb[c * HWn];
    }
    __syncthreads();
    float* dst = xT + pix0 * 128;
#pragma unroll 8
    for (int i = 0; i < 32; ++i) {
        const int o = t + 256 * i;
        dst[o] = Tl[o & 127][o >> 7];
    }
}

// One fused residual block, 16 pixels / 512 threads, NHWC, k-major K.
// Load batches are pinned in-flight with sched_barrier(0) fences.
__global__ __launch_bounds__(512, 6) void fused_stage(
    const float* __restrict__ xT, const short* __restrict__ wb,
    const short* __restrict__ owb, const float* __restrict__ obv,
    const float* __restrict__ gv, const float* __restrict__ bv,
    const float* __restrict__ mv, const float* __restrict__ vv,
    float* __restrict__ outT, float* __restrict__ outC, int dil, int last)
{
    __shared__ short S[16 * KPAD];            // im2col tile S[p][K'], 37120B
    __shared__ float offL[16][18];
    __shared__ float maskL[16][9];

    const int t   = threadIdx.x;
    const int l   = t & 63;
    const int wv  = t >> 6;                   // wave 0..7

    // XCD-aware bijective swizzle: 1152 blocks = 8 XCDs x 144 contiguous
    const int bid = blockIdx.x;
    const int swz = (bid & 7) * 144 + (bid >> 3);
    const int pix0 = swz * 16;
    const int b   = pix0 / HWn;
    const int sp0 = pix0 - b * HWn;
    const int hy  = sp0 / Wn;
    const int wx0 = sp0 - hy * Wn;
    const int basep = b * HWn;

    // ---- gather-int: 3 batches x 6 loads, fenced load->consume ----
#pragma unroll
    for (int bch = 0; bch < 3; ++bch) {
        float2 vle[6];
        float  mks[6];
#pragma unroll
        for (int u = 0; u < 6; ++u) {
            const int i  = bch * 6 + u;
            const int di = i / 9;
            const int k  = i - di * 9;
            const int pp = wv * 2 + di;
            const int iy = hy + (k / 3 - 1) * dil;
            const int ix = wx0 + pp + (k % 3 - 1) * dil;
            const bool v = (iy >= 0) && (iy < Hn) && (ix >= 0) && (ix < Wn);
            const int aof = __builtin_amdgcn_readfirstlane(v ? (basep + iy * Wn + ix) : basep);
            mks[u] = v ? 1.f : 0.f;
            vle[u] = ((const float2*)(xT + aof * 128))[l];
        }
        SB();                                   // pin: all 6 loads in flight
#pragma unroll
        for (int u = 0; u < 6; ++u) {
            const int i  = bch * 6 + u;
            const int di = i / 9;
            const int k  = i - di * 9;
            const int pp = wv * 2 + di;
            ((unsigned*)&S[pp * KPAD + k * 128])[l] = pack2(vle[u].x * mks[u], vle[u].y * mks[u]);
        }
    }
    __syncthreads();

    // ---- offconv GEMM: 3 batches x 3 (A,B) frag pairs, fenced ----
    const int mh = wv & 1, ks = wv >> 1;
    f32x4 oacc = {0.f, 0.f, 0.f, 0.f};
    {
        const short* oarow = owb + (mh * 16 + (l & 15)) * KCn + ks * 288 + ((l >> 4) * 8);
        const short* srow  = &S[(l & 15) * KPAD + ks * 288 + ((l >> 4) * 8)];
#pragma unroll
        for (int bch = 0; bch < 3; ++bch) {
            bf16x8 af[3], bf[3];
#pragma unroll
            for (int u = 0; u < 3; ++u) af[u] = *(const bf16x8*)(oarow + (bch * 3 + u) * 32);
#pragma unroll
            for (int u = 0; u < 3; ++u) bf[u] = *(const bf16x8*)(srow  + (bch * 3 + u) * 32);
            SB();
#pragma unroll
            for (int u = 0; u < 3; ++u)
                oacc = __builtin_amdgcn_mfma_f32_16x16x32_bf16(af[u], bf[u], oacc, 0, 0, 0);
        }
    }
    __syncthreads();                           // S(int) reads done
    float* red = (float*)S;                    // 8 waves x 64 lanes x f32x4 = 8KB
    *(f32x4*)&red[wv * 256 + l * 4] = oacc;
    __syncthreads();
    if (wv < 2) {
        f32x4 s0 = *(const f32x4*)&red[(0 * 2 + wv) * 256 + l * 4];
        f32x4 s1 = *(const f32x4*)&red[(1 * 2 + wv) * 256 + l * 4];
        f32x4 s2 = *(const f32x4*)&red[(2 * 2 + wv) * 256 + l * 4];
        f32x4 s3 = *(const f32x4*)&red[(3 * 2 + wv) * 256 + l * 4];
        f32x4 sm = (s0 + s1) + (s2 + s3);
#pragma unroll
        for (int r = 0; r < 4; ++r) {
            int oc = wv * 16 + ((l >> 4) << 2) + r;
            if (oc < 18) {
                offL[l & 15][oc] = sm[r] + obv[oc];
            } else if (oc < 27) {
                float z = sm[r] + obv[oc];
                maskL[l & 15][oc - 18] = 1.f / (1.f + expf(-z));
            }
        }
    }
    __syncthreads();                           // offL/maskL ready

    // ---- bilinear params: lane j (<18) computes set (pp=wv*2+j/9, k=j%9) ----
    int pw0i = 0, pw1i = 0, pw2i = 0, pw3i = 0, pa0 = 0, pa1 = 0, pdx = 0;
    if (l < 18) {
        const int p = wv * 2 + l / 9;
        const int k = l - 9 * (l / 9);
        const float offy = offL[p][2 * k];
        const float offx = offL[p][2 * k + 1];
        const float m    = maskL[p][k];
        const float py = (float)(hy + (k / 3 - 1) * dil) + offy;
        const float px = (float)(wx0 + p + (k % 3 - 1) * dil) + offx;
        const float y0f = floorf(py), x0f = floorf(px);
        const float ly = py - y0f, lx = px - x0f;
        const int y0 = (int)y0f, x0 = (int)x0f;
        const float yv0 = (y0 >= 0 && y0 < Hn)      ? 1.f : 0.f;
        const float yv1 = (y0 >= -1 && y0 < Hn - 1) ? 1.f : 0.f;
        const float xv0 = (x0 >= 0 && x0 < Wn)      ? 1.f : 0.f;
        const float xv1 = (x0 >= -1 && x0 < Wn - 1) ? 1.f : 0.f;
        const float wy0 = (1.f - ly) * yv0 * m;
        const float wy1 = ly * yv1 * m;
        const float wxa = (1.f - lx) * xv0;
        const float wxb = lx * xv1;
        pw0i = __float_as_int(wy0 * wxa);
        pw1i = __float_as_int(wy0 * wxb);
        pw2i = __float_as_int(wy1 * wxa);
        pw3i = __float_as_int(wy1 * wxb);
        const int y0c = min(max(y0, 0), Hn - 1), y1c = min(max(y0 + 1, 0), Hn - 1);
        const int x0c = min(max(x0, 0), Wn - 1), x1c = min(max(x0 + 1, 0), Wn - 1);
        pa0 = (basep + y0c * Wn + x0c) * 128;
        pa1 = (basep + y1c * Wn + x1c) * 128;
        pdx = (x1c - x0c) * 128;
    }

    // ---- gather-bil: 6 batches x (3 taps x 4 loads), fenced ----
#pragma unroll
    for (int bch = 0; bch < 6; ++bch) {
        float2 v00[3], v01[3], v10[3], v11[3];
        float  w00[3], w01[3], w10[3], w11[3];
#pragma unroll
        for (int u = 0; u < 3; ++u) {
            const int i = bch * 3 + u;
            w00[u] = __int_as_float(__builtin_amdgcn_readlane(pw0i, i));
            w01[u] = __int_as_float(__builtin_amdgcn_readlane(pw1i, i));
            w10[u] = __int_as_float(__builtin_amdgcn_readlane(pw2i, i));
            w11[u] = __int_as_float(__builtin_amdgcn_readlane(pw3i, i));
            const int a00 = __builtin_amdgcn_readlane(pa0, i);
            const int a11 = __builtin_amdgcn_readlane(pa1, i);
            const int dxk = __builtin_amdgcn_readlane(pdx, i);
            const float* xp = xT + a00;
            const float* xq = xT + a11;
            v00[u] = ((const float2*)xp)[l];
            v01[u] = ((const float2*)(xp + dxk))[l];
            v10[u] = ((const float2*)(xq - dxk))[l];
            v11[u] = ((const float2*)xq)[l];
        }
        SB();                                   // pin: all 12 loads in flight
#pragma unroll
        for (int u = 0; u < 3; ++u) {
            const int i  = bch * 3 + u;
            const int di = i / 9;
            const int k  = i - di * 9;
            const int pp = wv * 2 + di;
            float s0 = w00[u] * v00[u].x + w01[u] * v01[u].x + w10[u] * v10[u].x + w11[u] * v11[u].x;
            float s1 = w00[u] * v00[u].y + w01[u] * v01[u].y + w10[u] * v10[u].y + w11[u] * v11[u].y;
            ((unsigned*)&S[pp * KPAD + k * 128])[l] = pack2(s0, s1);
        }
    }
    __syncthreads();

    // ---- dconv GEMM: 6 batches x 6 (A,B) frag pairs, fenced; A first ----
    f32x4 dacc = {0.f, 0.f, 0.f, 0.f};
    {
        const short* darow = wb + (wv * 16 + (l & 15)) * KCn + ((l >> 4) * 8);
        const short* srow  = &S[(l & 15) * KPAD + ((l >> 4) * 8)];
#pragma unroll
        for (int bch = 0; bch < 6; ++bch) {
            bf16x8 af[6], bf[6];
#pragma unroll
            for (int u = 0; u < 6; ++u) af[u] = *(const bf16x8*)(darow + (bch * 6 + u) * 32);
#pragma unroll
            for (int u = 0; u < 6; ++u) bf[u] = *(const bf16x8*)(srow  + (bch * 6 + u) * 32);
            SB();                               // pin: 6 global + 6 LDS in flight
#pragma unroll
            for (int u = 0; u < 6; ++u)
                dacc = __builtin_amdgcn_mfma_f32_16x16x32_bf16(af[u], bf[u], dacc, 0, 0, 0);
        }
    }

    // ---- epilogue: BN + ReLU + residual ----
    const int pp  = l & 15;
    const int ocb = wv * 16 + ((l >> 4) << 2);
    if (last) {
#pragma unroll
        for (int r = 0; r < 4; ++r) {
            const int oc = ocb + r;
            const float sc = gv[oc] * rsqrtf(vv[oc] + EPSn);
            float y = (dacc[r] - mv[oc]) * sc + bv[oc];
            y = fmaxf(y, 0.f);
            y += xT[(pix0 + pp) * 128 + oc];
            outC[b * CHWn + oc * HWn + sp0 + pp] = y;
        }
    } else {
        __syncthreads();                       // all S reads done; alias O on S
        float* O = (float*)S;                  // O[16][132]
#pragma unroll
        for (int r = 0; r < 4; ++r) {
            const int oc = ocb + r;
            const float sc = gv[oc] * rsqrtf(vv[oc] + EPSn);
            float y = (dacc[r] - mv[oc]) * sc + bv[oc];
            O[pp * 132 + oc] = fmaxf(y, 0.f);
        }
        __syncthreads();
        const int o  = t * 4;                  // 0..2047
        const int qp = o >> 7, qc = o & 127;
        f32x4 yv = *(f32x4*)&O[qp * 132 + qc];
        f32x4 rv = *(const f32x4*)&xT[(pix0 + qp) * 128 + qc];
        yv += rv;
        *(f32x4*)&outT[(pix0 + qp) * 128 + qc] = yv;
    }
}

extern "C" void kernel_launch(void* const* d_in, const int* in_sizes, int n_in,
                              void* d_out, int out_size, void* d_ws, size_t ws_size,
                              hipStream_t stream) {
    (void)in_sizes; (void)n_in; (void)out_size; (void)ws_size;

    const float* hu = (const float*)d_in[0];

    short* wb  = (short*)d_ws;                    // 3 * 147456 shorts
    short* owb = wb + 3 * Cn * KCn;               // 3 * 36864 shorts
    float* T0  = (float*)(owb + 3 * 32 * KCn);    // Bn*CHWn floats (NHWC)
    float* T1  = T0 + Bn * CHWn;                  // Bn*CHWn floats (NHWC)

    for (int i = 0; i < 3; ++i) {
        cvt_w_kernel<<<(Cn * KCn + 255) / 256, 256, 0, stream>>>(
            (const float*)d_in[3 + 7 * i], wb + i * Cn * KCn);
        cvt_ow_kernel<<<(32 * KCn + 255) / 256, 256, 0, stream>>>(
            (const float*)d_in[1 + 7 * i], owb + i * 32 * KCn);
    }

    nchw2nhwc<<<(Bn * HWn) / 64, 256, 0, stream>>>(hu, T0);

    const int dils[3] = {2, 4, 8};
    const float* ins[3] = {T0, T1, T0};
    float*       outsT[3] = {T1, T0, nullptr};
    const int nblk = (Bn * HWn) / 16;             // 1152

    for (int i = 0; i < 3; ++i) {
        const float* obv = (const float*)d_in[2 + 7 * i];
        const float* gv  = (const float*)d_in[4 + 7 * i];
        const float* bv  = (const float*)d_in[5 + 7 * i];
        const float* mv  = (const float*)d_in[6 + 7 * i];
        const float* vv  = (const float*)d_in[7 + 7 * i];
        const int last = (i == 2);

        fused_stage<<<nblk, 512, 0, stream>>>(
            ins[i], wb + i * Cn * KCn, owb + i * 32 * KCn, obv,
            gv, bv, mv, vv, outsT[i], last ? (float*)d_out : nullptr,
            dils[i], last);
    }
}

// Round 13
// 154.538 us; speedup vs baseline: 1.7110x; 1.7110x over previous
//
#include <hip/hip_runtime.h>
#include <math.h>

constexpr int Bn  = 2;
constexpr int Cn  = 128;
constexpr int Hn  = 96;
constexpr int Wn  = 96;
constexpr int HWn = Hn * Wn;        // 9216
constexpr int CHWn = Cn * HWn;      // 1179648
constexpr int KCn = Cn * 9;         // 1152
constexpr float EPSn = 1e-5f;
constexpr int KPAD = 1160;          // LDS row stride in shorts (2320B, 16B-aligned)

typedef short bf16x8 __attribute__((ext_vector_type(8)));
typedef float f32x4  __attribute__((ext_vector_type(4)));

static __device__ inline short f2bf(float f) {
    union { float f; unsigned u; } v; v.f = f;
    unsigned r = v.u + 0x7fff + ((v.u >> 16) & 1);
    return (short)(r >> 16);
}
// packed bf16 convert: lo = bf16(a), hi = bf16(b)
static __device__ inline unsigned pack2(float a, float b) {
    unsigned r;
    asm("v_cvt_pk_bf16_f32 %0, %1, %2" : "=v"(r) : "v"(a), "v"(b));
    return r;
}

// Fragment-shuffled dconv weights:
// wbs[((wv*36 + j)*64 + l)*8 + e] = w_kmajor[row = wv*16 + (l&15)][j*32 + (l>>4)*8 + e]
// where w_kmajor[o][k*128+c] = w[o][c*9+k]. Each A-frag load becomes 1KB contiguous.
__global__ __launch_bounds__(256) void cvt_w_shuf(
    const float* __restrict__ w, short* __restrict__ wbs)
{
    int t = blockIdx.x * 256 + threadIdx.x;   // 147456
    if (t >= Cn * KCn) return;
    int e = t & 7, l = (t >> 3) & 63, rest = t >> 9;   // rest 0..287
    int j = rest % 36, wv = rest / 36;
    int lr = l & 15, lq = l >> 4;
    int o = wv * 16 + lr;
    int kidx = j * 32 + lq * 8 + e;
    int k = kidx >> 7, c = kidx & 127;
    wbs[t] = f2bf(w[o * KCn + c * 9 + k]);
}

// Fragment-shuffled offconv weights (wave wv -> mh=wv&1, ks=wv>>1):
// owbs[((wv*9 + kk)*64 + l)*8 + e] = row (mh*16+l&15), K' = ks*288 + kk*32 + (l>>4)*8 + e
__global__ __launch_bounds__(256) void cvt_ow_shuf(
    const float* __restrict__ ow, short* __restrict__ owbs)
{
    int t = blockIdx.x * 256 + threadIdx.x;   // 36864
    if (t >= 32 * KCn) return;
    int e = t & 7, l = (t >> 3) & 63, rest = t >> 9;   // rest 0..71
    int kk = rest % 9, wv = rest / 9;
    int mh = wv & 1, ks = wv >> 1;
    int lr = l & 15, lq = l >> 4;
    int o = mh * 16 + lr;
    int kidx = ks * 288 + kk * 32 + lq * 8 + e;
    int k = kidx >> 7, c = kidx & 127;
    owbs[t] = (o < 27) ? f2bf(ow[o * KCn + c * 9 + k]) : (short)0;
}

// NCHW -> NHWC (global-pixel-major)
__global__ __launch_bounds__(256) void nchw2nhwc(
    const float* __restrict__ x, float* __restrict__ xT)
{
    __shared__ float Tl[128][65];
    const int t = threadIdx.x;
    const int pix0 = blockIdx.x * 64;
    const int b   = pix0 / HWn;
    const int sp0 = pix0 - b * HWn;
    const float* xb = x + b * CHWn + sp0 + (t & 63);
    const int c0 = t >> 6;
#pragma unroll 8
    for (int i = 0; i < 32; ++i) {
        const int c = c0 + 4 * i;
        Tl[c][t & 63] = xb[c * HWn];
    }
    __syncthreads();
    float* dst = xT + pix0 * 128;
#pragma unroll 8
    for (int i = 0; i < 32; ++i) {
        const int o = t + 256 * i;
        dst[o] = Tl[o & 127][o >> 7];
    }
}

// One fused residual block, 16 pixels / 512 threads, NHWC, k-major K,
// fragment-shuffled weights (all A-loads 1KB contiguous).
__global__ __launch_bounds__(512, 6) void fused_stage(
    const float* __restrict__ xT, const short* __restrict__ wbs,
    const short* __restrict__ owbs, const float* __restrict__ obv,
    const float* __restrict__ gv, const float* __restrict__ bv,
    const float* __restrict__ mv, const float* __restrict__ vv,
    float* __restrict__ outT, float* __restrict__ outC, int dil, int last)
{
    __shared__ short S[16 * KPAD];            // im2col tile S[p][K'], 37120B
    __shared__ float offL[16][18];
    __shared__ float maskL[16][9];

    const int t   = threadIdx.x;
    const int l   = t & 63;
    const int wv  = t >> 6;                   // wave 0..7
    const int lh  = l >> 5;                   // pixel half (gather-int)
    const int lc  = l & 31;                   // channel quad (gather-int)

    // XCD-aware bijective swizzle: 1152 blocks = 8 XCDs x 144 contiguous
    const int bid = blockIdx.x;
    const int swz = (bid & 7) * 144 + (bid >> 3);
    const int pix0 = swz * 16;
    const int b   = pix0 / HWn;
    const int sp0 = pix0 - b * HWn;
    const int hy  = sp0 / Wn;
    const int wx0 = sp0 - hy * Wn;
    const int basep = b * HWn;

    // ---- gather-int: 9 float4 loads (lane-half = pixel), 3 batches ----
#pragma unroll
    for (int bch = 0; bch < 3; ++bch) {
        float4 vle[3];
        float  mks[3];
#pragma unroll
        for (int u = 0; u < 3; ++u) {
            const int k  = bch * 3 + u;
            const int pp = wv * 2 + lh;
            const int iy = hy + (k / 3 - 1) * dil;
            const int ix = wx0 + pp + (k % 3 - 1) * dil;
            const bool v = (iy >= 0) && (iy < Hn) && (ix >= 0) && (ix < Wn);
            const int aof = v ? (basep + iy * Wn + ix) : basep;
            mks[u] = v ? 1.f : 0.f;
            vle[u] = ((const float4*)(xT + aof * 128))[lc];
        }
#pragma unroll
        for (int u = 0; u < 3; ++u) {
            const int k  = bch * 3 + u;
            const int pp = wv * 2 + lh;
            uint2 pk;
            pk.x = pack2(vle[u].x * mks[u], vle[u].y * mks[u]);
            pk.y = pack2(vle[u].z * mks[u], vle[u].w * mks[u]);
            ((uint2*)&S[pp * KPAD + k * 128])[lc] = pk;
        }
    }
    __syncthreads();

    // ---- offconv GEMM: A from shuffled owbs (contiguous 1KB/load) ----
    f32x4 oacc = {0.f, 0.f, 0.f, 0.f};
    {
        const short* oarow = owbs + (wv * 9) * 512 + l * 8;
        const int ks = wv >> 1;
        const short* srow  = &S[(l & 15) * KPAD + ks * 288 + ((l >> 4) * 8)];
#pragma unroll
        for (int bch = 0; bch < 3; ++bch) {
            bf16x8 af[3], bf[3];
#pragma unroll
            for (int u = 0; u < 3; ++u) af[u] = *(const bf16x8*)(oarow + (bch * 3 + u) * 512);
#pragma unroll
            for (int u = 0; u < 3; ++u) bf[u] = *(const bf16x8*)(srow  + (bch * 3 + u) * 32);
#pragma unroll
            for (int u = 0; u < 3; ++u)
                oacc = __builtin_amdgcn_mfma_f32_16x16x32_bf16(af[u], bf[u], oacc, 0, 0, 0);
        }
    }
    __syncthreads();                           // S(int) reads done
    float* red = (float*)S;                    // 8 waves x 64 lanes x f32x4 = 8KB
    *(f32x4*)&red[wv * 256 + l * 4] = oacc;
    __syncthreads();
    if (wv < 2) {
        f32x4 s0 = *(const f32x4*)&red[(0 * 2 + wv) * 256 + l * 4];
        f32x4 s1 = *(const f32x4*)&red[(1 * 2 + wv) * 256 + l * 4];
        f32x4 s2 = *(const f32x4*)&red[(2 * 2 + wv) * 256 + l * 4];
        f32x4 s3 = *(const f32x4*)&red[(3 * 2 + wv) * 256 + l * 4];
        f32x4 sm = (s0 + s1) + (s2 + s3);
#pragma unroll
        for (int r = 0; r < 4; ++r) {
            int oc = wv * 16 + ((l >> 4) << 2) + r;
            if (oc < 18) {
                offL[l & 15][oc] = sm[r] + obv[oc];
            } else if (oc < 27) {
                float z = sm[r] + obv[oc];
                maskL[l & 15][oc - 18] = 1.f / (1.f + expf(-z));
            }
        }
    }
    __syncthreads();                           // offL/maskL ready

    // ---- bilinear params: lane j (<18) computes set (pp=wv*2+j/9, k=j%9) ----
    int pw0i = 0, pw1i = 0, pw2i = 0, pw3i = 0, pa0 = 0, pa1 = 0, pdx = 0;
    if (l < 18) {
        const int p = wv * 2 + l / 9;
        const int k = l - 9 * (l / 9);
        const float offy = offL[p][2 * k];
        const float offx = offL[p][2 * k + 1];
        const float m    = maskL[p][k];
        const float py = (float)(hy + (k / 3 - 1) * dil) + offy;
        const float px = (float)(wx0 + p + (k % 3 - 1) * dil) + offx;
        const float y0f = floorf(py), x0f = floorf(px);
        const float ly = py - y0f, lx = px - x0f;
        const int y0 = (int)y0f, x0 = (int)x0f;
        const float yv0 = (y0 >= 0 && y0 < Hn)      ? 1.f : 0.f;
        const float yv1 = (y0 >= -1 && y0 < Hn - 1) ? 1.f : 0.f;
        const float xv0 = (x0 >= 0 && x0 < Wn)      ? 1.f : 0.f;
        const float xv1 = (x0 >= -1 && x0 < Wn - 1) ? 1.f : 0.f;
        const float wy0 = (1.f - ly) * yv0 * m;
        const float wy1 = ly * yv1 * m;
        const float wxa = (1.f - lx) * xv0;
        const float wxb = lx * xv1;
        pw0i = __float_as_int(wy0 * wxa);
        pw1i = __float_as_int(wy0 * wxb);
        pw2i = __float_as_int(wy1 * wxa);
        pw3i = __float_as_int(wy1 * wxb);
        const int y0c = min(max(y0, 0), Hn - 1), y1c = min(max(y0 + 1, 0), Hn - 1);
        const int x0c = min(max(x0, 0), Wn - 1), x1c = min(max(x0 + 1, 0), Wn - 1);
        pa0 = (basep + y0c * Wn + x0c) * 128;
        pa1 = (basep + y1c * Wn + x1c) * 128;
        pdx = (x1c - x0c) * 128;
    }

    // ---- gather-bil: 6 batches x (3 taps x 4 loads) ----
#pragma unroll
    for (int bch = 0; bch < 6; ++bch) {
        float2 v00[3], v01[3], v10[3], v11[3];
        float  w00[3], w01[3], w10[3], w11[3];
#pragma unroll
        for (int u = 0; u < 3; ++u) {
            const int i = bch * 3 + u;
            w00[u] = __int_as_float(__builtin_amdgcn_readlane(pw0i, i));
            w01[u] = __int_as_float(__builtin_amdgcn_readlane(pw1i, i));
            w10[u] = __int_as_float(__builtin_amdgcn_readlane(pw2i, i));
            w11[u] = __int_as_float(__builtin_amdgcn_readlane(pw3i, i));
            const int a00 = __builtin_amdgcn_readlane(pa0, i);
            const int a11 = __builtin_amdgcn_readlane(pa1, i);
            const int dxk = __builtin_amdgcn_readlane(pdx, i);
            const float* xp = xT + a00;
            const float* xq = xT + a11;
            v00[u] = ((const float2*)xp)[l];
            v01[u] = ((const float2*)(xp + dxk))[l];
            v10[u] = ((const float2*)(xq - dxk))[l];
            v11[u] = ((const float2*)xq)[l];
        }
#pragma unroll
        for (int u = 0; u < 3; ++u) {
            const int i  = bch * 3 + u;
            const int di = i / 9;
            const int k  = i - di * 9;
            const int pp = wv * 2 + di;
            float s0 = w00[u] * v00[u].x + w01[u] * v01[u].x + w10[u] * v10[u].x + w11[u] * v11[u].x;
            float s1 = w00[u] * v00[u].y + w01[u] * v01[u].y + w10[u] * v10[u].y + w11[u] * v11[u].y;
            ((unsigned*)&S[pp * KPAD + k * 128])[l] = pack2(s0, s1);
        }
    }
    __syncthreads();

    // ---- dconv GEMM: A from shuffled wbs (contiguous 1KB/load) ----
    f32x4 dacc = {0.f, 0.f, 0.f, 0.f};
    {
        const short* darow = wbs + (wv * 36) * 512 + l * 8;
        const short* srow  = &S[(l & 15) * KPAD + ((l >> 4) * 8)];
#pragma unroll
        for (int bch = 0; bch < 6; ++bch) {
            bf16x8 af[6], bf[6];
#pragma unroll
            for (int u = 0; u < 6; ++u) af[u] = *(const bf16x8*)(darow + (bch * 6 + u) * 512);
#pragma unroll
            for (int u = 0; u < 6; ++u) bf[u] = *(const bf16x8*)(srow  + (bch * 6 + u) * 32);
#pragma unroll
            for (int u = 0; u < 6; ++u)
                dacc = __builtin_amdgcn_mfma_f32_16x16x32_bf16(af[u], bf[u], dacc, 0, 0, 0);
        }
    }

    // ---- epilogue: BN + ReLU + residual ----
    const int pp  = l & 15;
    const int ocb = wv * 16 + ((l >> 4) << 2);
    if (last) {
#pragma unroll
        for (int r = 0; r < 4; ++r) {
            const int oc = ocb + r;
            const float sc = gv[oc] * rsqrtf(vv[oc] + EPSn);
            float y = (dacc[r] - mv[oc]) * sc + bv[oc];
            y = fmaxf(y, 0.f);
            y += xT[(pix0 + pp) * 128 + oc];
            outC[b * CHWn + oc * HWn + sp0 + pp] = y;
        }
    } else {
        __syncthreads();                       // all S reads done; alias O on S
        float* O = (float*)S;                  // O[16][132]
#pragma unroll
        for (int r = 0; r < 4; ++r) {
            const int oc = ocb + r;
            const float sc = gv[oc] * rsqrtf(vv[oc] + EPSn);
            float y = (dacc[r] - mv[oc]) * sc + bv[oc];
            O[pp * 132 + oc] = fmaxf(y, 0.f);
        }
        __syncthreads();
        const int o  = t * 4;                  // 0..2047
        const int qp = o >> 7, qc = o & 127;
        f32x4 yv = *(f32x4*)&O[qp * 132 + qc];
        f32x4 rv = *(const f32x4*)&xT[(pix0 + qp) * 128 + qc];
        yv += rv;
        *(f32x4*)&outT[(pix0 + qp) * 128 + qc] = yv;
    }
}

extern "C" void kernel_launch(void* const* d_in, const int* in_sizes, int n_in,
                              void* d_out, int out_size, void* d_ws, size_t ws_size,
                              hipStream_t stream) {
    (void)in_sizes; (void)n_in; (void)out_size; (void)ws_size;

    const float* hu = (const float*)d_in[0];

    short* wbs  = (short*)d_ws;                   // 3 * 147456 shorts
    short* owbs = wbs + 3 * Cn * KCn;             // 3 * 36864 shorts
    float* T0   = (float*)(owbs + 3 * 32 * KCn);  // Bn*CHWn floats (NHWC)
    float* T1   = T0 + Bn * CHWn;                 // Bn*CHWn floats (NHWC)

    for (int i = 0; i < 3; ++i) {
        cvt_w_shuf<<<(Cn * KCn + 255) / 256, 256, 0, stream>>>(
            (const float*)d_in[3 + 7 * i], wbs + i * Cn * KCn);
        cvt_ow_shuf<<<(32 * KCn + 255) / 256, 256, 0, stream>>>(
            (const float*)d_in[1 + 7 * i], owbs + i * 32 * KCn);
    }

    nchw2nhwc<<<(Bn * HWn) / 64, 256, 0, stream>>>(hu, T0);

    const int dils[3] = {2, 4, 8};
    const float* ins[3] = {T0, T1, T0};
    float*       outsT[3] = {T1, T0, nullptr};
    const int nblk = (Bn * HWn) / 16;             // 1152

    for (int i = 0; i < 3; ++i) {
        const float* obv = (const float*)d_in[2 + 7 * i];
        const float* gv  = (const float*)d_in[4 + 7 * i];
        const float* bv  = (const float*)d_in[5 + 7 * i];
        const float* mv  = (const float*)d_in[6 + 7 * i];
        const float* vv  = (const float*)d_in[7 + 7 * i];
        const int last = (i == 2);

        fused_stage<<<nblk, 512, 0, stream>>>(
            ins[i], wbs + i * Cn * KCn, owbs + i * 32 * KCn, obv,
            gv, bv, mv, vv, outsT[i], last ? (float*)d_out : nullptr,
            dils[i], last);
    }
}

// Round 14
// 121.494 us; speedup vs baseline: 2.1763x; 1.2720x over previous
//
#include <hip/hip_runtime.h>
#include <math.h>

constexpr int Bn  = 2;
constexpr int Cn  = 128;
constexpr int Hn  = 96;
constexpr int Wn  = 96;
constexpr int HWn = Hn * Wn;        // 9216
constexpr int CHWn = Cn * HWn;      // 1179648
constexpr int KCn = Cn * 9;         // 1152
constexpr float EPSn = 1e-5f;
constexpr int KPAD = 1160;          // LDS row stride in shorts (2320B, 16B-aligned)

typedef short bf16x8 __attribute__((ext_vector_type(8)));
typedef float f32x4  __attribute__((ext_vector_type(4)));

static __device__ inline short f2bf(float f) {
    union { float f; unsigned u; } v; v.f = f;
    unsigned r = v.u + 0x7fff + ((v.u >> 16) & 1);
    return (short)(r >> 16);
}
// packed bf16 convert: lo = bf16(a), hi = bf16(b)
static __device__ inline unsigned pack2(float a, float b) {
    unsigned r;
    asm("v_cvt_pk_bf16_f32 %0, %1, %2" : "=v"(r) : "v"(a), "v"(b));
    return r;
}

// Fragment-shuffled dconv weights (see round 13; each A-load = 1KB contiguous)
__global__ __launch_bounds__(256) void cvt_w_shuf(
    const float* __restrict__ w, short* __restrict__ wbs)
{
    int t = blockIdx.x * 256 + threadIdx.x;   // 147456
    if (t >= Cn * KCn) return;
    int e = t & 7, l = (t >> 3) & 63, rest = t >> 9;   // rest 0..287
    int j = rest % 36, wv = rest / 36;
    int lr = l & 15, lq = l >> 4;
    int o = wv * 16 + lr;
    int kidx = j * 32 + lq * 8 + e;
    int k = kidx >> 7, c = kidx & 127;
    wbs[t] = f2bf(w[o * KCn + c * 9 + k]);
}

// Fragment-shuffled offconv weights
__global__ __launch_bounds__(256) void cvt_ow_shuf(
    const float* __restrict__ ow, short* __restrict__ owbs)
{
    int t = blockIdx.x * 256 + threadIdx.x;   // 36864
    if (t >= 32 * KCn) return;
    int e = t & 7, l = (t >> 3) & 63, rest = t >> 9;   // rest 0..71
    int kk = rest % 9, wv = rest / 9;
    int mh = wv & 1, ks = wv >> 1;
    int lr = l & 15, lq = l >> 4;
    int o = mh * 16 + lr;
    int kidx = ks * 288 + kk * 32 + lq * 8 + e;
    int k = kidx >> 7, c = kidx & 127;
    owbs[t] = (o < 27) ? f2bf(ow[o * KCn + c * 9 + k]) : (short)0;
}

// NCHW -> NHWC, dual output: f32 (residual-exact) + bf16 (gather path)
__global__ __launch_bounds__(256) void nchw2nhwc(
    const float* __restrict__ x, float* __restrict__ xTf,
    unsigned short* __restrict__ xTb)
{
    __shared__ float Tl[128][65];
    const int t = threadIdx.x;
    const int pix0 = blockIdx.x * 64;
    const int b   = pix0 / HWn;
    const int sp0 = pix0 - b * HWn;
    const float* xb = x + b * CHWn + sp0 + (t & 63);
    const int c0 = t >> 6;
#pragma unroll 8
    for (int i = 0; i < 32; ++i) {
        const int c = c0 + 4 * i;
        Tl[c][t & 63] = xb[c * HWn];
    }
    __syncthreads();
    float* dstf = xTf + pix0 * 128;
    unsigned short* dstb = xTb + pix0 * 128;
#pragma unroll 8
    for (int i = 0; i < 32; ++i) {
        const int o = t + 256 * i;
        float v = Tl[o & 127][o >> 7];
        dstf[o] = v;
        dstb[o] = (unsigned short)f2bf(v);
    }
}

// One fused residual block, 16 pixels / 512 threads, NHWC bf16 gathers,
// f32 residual, fragment-shuffled weights.
__global__ __launch_bounds__(512, 6) void fused_stage(
    const unsigned short* __restrict__ xTb, const float* __restrict__ xTf,
    const short* __restrict__ wbs, const short* __restrict__ owbs,
    const float* __restrict__ obv,
    const float* __restrict__ gv, const float* __restrict__ bv,
    const float* __restrict__ mv, const float* __restrict__ vv,
    float* __restrict__ outTf, unsigned short* __restrict__ outTb,
    float* __restrict__ outC, int dil, int last)
{
    __shared__ short S[16 * KPAD];            // im2col tile S[p][K'], 37120B
    __shared__ float offL[16][18];
    __shared__ float maskL[16][9];

    const int t   = threadIdx.x;
    const int l   = t & 63;
    const int wv  = t >> 6;                   // wave 0..7
    const int lh  = l >> 5;                   // pixel half (gather-int)
    const int lc  = l & 31;                   // channel quad (gather-int)

    // XCD-aware bijective swizzle: 1152 blocks = 8 XCDs x 144 contiguous
    const int bid = blockIdx.x;
    const int swz = (bid & 7) * 144 + (bid >> 3);
    const int pix0 = swz * 16;
    const int b   = pix0 / HWn;
    const int sp0 = pix0 - b * HWn;
    const int hy  = sp0 / Wn;
    const int wx0 = sp0 - hy * Wn;
    const int basep = b * HWn;

    // ---- gather-int: bf16 source, pure masked copy (uint2 = 4ch) ----
#pragma unroll
    for (int bch = 0; bch < 3; ++bch) {
        uint2 vle[3];
#pragma unroll
        for (int u = 0; u < 3; ++u) {
            const int k  = bch * 3 + u;
            const int pp = wv * 2 + lh;
            const int iy = hy + (k / 3 - 1) * dil;
            const int ix = wx0 + pp + (k % 3 - 1) * dil;
            const bool v = (iy >= 0) && (iy < Hn) && (ix >= 0) && (ix < Wn);
            const int aof = v ? (basep + iy * Wn + ix) : basep;
            uint2 val = ((const uint2*)(xTb + aof * 128))[lc];
            vle[u].x = v ? val.x : 0u;
            vle[u].y = v ? val.y : 0u;
        }
#pragma unroll
        for (int u = 0; u < 3; ++u) {
            const int k  = bch * 3 + u;
            const int pp = wv * 2 + lh;
            ((uint2*)&S[pp * KPAD + k * 128])[lc] = vle[u];
        }
    }
    __syncthreads();

    // ---- offconv GEMM: A from shuffled owbs (contiguous 1KB/load) ----
    f32x4 oacc = {0.f, 0.f, 0.f, 0.f};
    {
        const short* oarow = owbs + (wv * 9) * 512 + l * 8;
        const int ks = wv >> 1;
        const short* srow  = &S[(l & 15) * KPAD + ks * 288 + ((l >> 4) * 8)];
#pragma unroll
        for (int bch = 0; bch < 3; ++bch) {
            bf16x8 af[3], bf[3];
#pragma unroll
            for (int u = 0; u < 3; ++u) af[u] = *(const bf16x8*)(oarow + (bch * 3 + u) * 512);
#pragma unroll
            for (int u = 0; u < 3; ++u) bf[u] = *(const bf16x8*)(srow  + (bch * 3 + u) * 32);
#pragma unroll
            for (int u = 0; u < 3; ++u)
                oacc = __builtin_amdgcn_mfma_f32_16x16x32_bf16(af[u], bf[u], oacc, 0, 0, 0);
        }
    }
    __syncthreads();                           // S(int) reads done
    float* red = (float*)S;                    // 8 waves x 64 lanes x f32x4 = 8KB
    *(f32x4*)&red[wv * 256 + l * 4] = oacc;
    __syncthreads();
    if (wv < 2) {
        f32x4 s0 = *(const f32x4*)&red[(0 * 2 + wv) * 256 + l * 4];
        f32x4 s1 = *(const f32x4*)&red[(1 * 2 + wv) * 256 + l * 4];
        f32x4 s2 = *(const f32x4*)&red[(2 * 2 + wv) * 256 + l * 4];
        f32x4 s3 = *(const f32x4*)&red[(3 * 2 + wv) * 256 + l * 4];
        f32x4 sm = (s0 + s1) + (s2 + s3);
#pragma unroll
        for (int r = 0; r < 4; ++r) {
            int oc = wv * 16 + ((l >> 4) << 2) + r;
            if (oc < 18) {
                offL[l & 15][oc] = sm[r] + obv[oc];
            } else if (oc < 27) {
                float z = sm[r] + obv[oc];
                maskL[l & 15][oc - 18] = 1.f / (1.f + expf(-z));
            }
        }
    }
    __syncthreads();                           // offL/maskL ready

    // ---- bilinear params: lane j (<18) computes set (pp=wv*2+j/9, k=j%9) ----
    int pw0i = 0, pw1i = 0, pw2i = 0, pw3i = 0, pa0 = 0, pa1 = 0, pdx = 0;
    if (l < 18) {
        const int p = wv * 2 + l / 9;
        const int k = l - 9 * (l / 9);
        const float offy = offL[p][2 * k];
        const float offx = offL[p][2 * k + 1];
        const float m    = maskL[p][k];
        const float py = (float)(hy + (k / 3 - 1) * dil) + offy;
        const float px = (float)(wx0 + p + (k % 3 - 1) * dil) + offx;
        const float y0f = floorf(py), x0f = floorf(px);
        const float ly = py - y0f, lx = px - x0f;
        const int y0 = (int)y0f, x0 = (int)x0f;
        const float yv0 = (y0 >= 0 && y0 < Hn)      ? 1.f : 0.f;
        const float yv1 = (y0 >= -1 && y0 < Hn - 1) ? 1.f : 0.f;
        const float xv0 = (x0 >= 0 && x0 < Wn)      ? 1.f : 0.f;
        const float xv1 = (x0 >= -1 && x0 < Wn - 1) ? 1.f : 0.f;
        const float wy0 = (1.f - ly) * yv0 * m;
        const float wy1 = ly * yv1 * m;
        const float wxa = (1.f - lx) * xv0;
        const float wxb = lx * xv1;
        pw0i = __float_as_int(wy0 * wxa);
        pw1i = __float_as_int(wy0 * wxb);
        pw2i = __float_as_int(wy1 * wxa);
        pw3i = __float_as_int(wy1 * wxb);
        const int y0c = min(max(y0, 0), Hn - 1), y1c = min(max(y0 + 1, 0), Hn - 1);
        const int x0c = min(max(x0, 0), Wn - 1), x1c = min(max(x0 + 1, 0), Wn - 1);
        pa0 = (basep + y0c * Wn + x0c) * 128;
        pa1 = (basep + y1c * Wn + x1c) * 128;
        pdx = (x1c - x0c) * 128;
    }

    // ---- gather-bil: bf16 source (uint = 2ch), unpack->FMA->pack ----
#pragma unroll
    for (int bch = 0; bch < 6; ++bch) {
        unsigned u00[3], u01[3], u10[3], u11[3];
        float    w00[3], w01[3], w10[3], w11[3];
#pragma unroll
        for (int u = 0; u < 3; ++u) {
            const int i = bch * 3 + u;
            w00[u] = __int_as_float(__builtin_amdgcn_readlane(pw0i, i));
            w01[u] = __int_as_float(__builtin_amdgcn_readlane(pw1i, i));
            w10[u] = __int_as_float(__builtin_amdgcn_readlane(pw2i, i));
            w11[u] = __int_as_float(__builtin_amdgcn_readlane(pw3i, i));
            const int a00 = __builtin_amdgcn_readlane(pa0, i);
            const int a11 = __builtin_amdgcn_readlane(pa1, i);
            const int dxk = __builtin_amdgcn_readlane(pdx, i);
            const unsigned short* xp = xTb + a00;
            const unsigned short* xq = xTb + a11;
            u00[u] = ((const unsigned*)xp)[l];
            u01[u] = ((const unsigned*)(xp + dxk))[l];
            u10[u] = ((const unsigned*)(xq - dxk))[l];
            u11[u] = ((const unsigned*)xq)[l];
        }
#pragma unroll
        for (int u = 0; u < 3; ++u) {
            const int i  = bch * 3 + u;
            const int di = i / 9;
            const int k  = i - di * 9;
            const int pp = wv * 2 + di;
            const float f00a = __int_as_float(u00[u] << 16);
            const float f00b = __int_as_float(u00[u] & 0xffff0000u);
            const float f01a = __int_as_float(u01[u] << 16);
            const float f01b = __int_as_float(u01[u] & 0xffff0000u);
            const float f10a = __int_as_float(u10[u] << 16);
            const float f10b = __int_as_float(u10[u] & 0xffff0000u);
            const float f11a = __int_as_float(u11[u] << 16);
            const float f11b = __int_as_float(u11[u] & 0xffff0000u);
            float s0 = w00[u] * f00a + w01[u] * f01a + w10[u] * f10a + w11[u] * f11a;
            float s1 = w00[u] * f00b + w01[u] * f01b + w10[u] * f10b + w11[u] * f11b;
            ((unsigned*)&S[pp * KPAD + k * 128])[l] = pack2(s0, s1);
        }
    }
    __syncthreads();

    // ---- dconv GEMM: A from shuffled wbs (contiguous 1KB/load) ----
    f32x4 dacc = {0.f, 0.f, 0.f, 0.f};
    {
        const short* darow = wbs + (wv * 36) * 512 + l * 8;
        const short* srow  = &S[(l & 15) * KPAD + ((l >> 4) * 8)];
#pragma unroll
        for (int bch = 0; bch < 6; ++bch) {
            bf16x8 af[6], bf[6];
#pragma unroll
            for (int u = 0; u < 6; ++u) af[u] = *(const bf16x8*)(darow + (bch * 6 + u) * 512);
#pragma unroll
            for (int u = 0; u < 6; ++u) bf[u] = *(const bf16x8*)(srow  + (bch * 6 + u) * 32);
#pragma unroll
            for (int u = 0; u < 6; ++u)
                dacc = __builtin_amdgcn_mfma_f32_16x16x32_bf16(af[u], bf[u], dacc, 0, 0, 0);
        }
    }

    // ---- epilogue: BN + ReLU + residual(f32) ----
    const int pp  = l & 15;
    const int ocb = wv * 16 + ((l >> 4) << 2);
    if (last) {
#pragma unroll
        for (int r = 0; r < 4; ++r) {
            const int oc = ocb + r;
            const float sc = gv[oc] * rsqrtf(vv[oc] + EPSn);
            float y = (dacc[r] - mv[oc]) * sc + bv[oc];
            y = fmaxf(y, 0.f);
            y += xTf[(pix0 + pp) * 128 + oc];
            outC[b * CHWn + oc * HWn + sp0 + pp] = y;
        }
    } else {
        __syncthreads();                       // all S reads done; alias O on S
        float* O = (float*)S;                  // O[16][132]
#pragma unroll
        for (int r = 0; r < 4; ++r) {
            const int oc = ocb + r;
            const float sc = gv[oc] * rsqrtf(vv[oc] + EPSn);
            float y = (dacc[r] - mv[oc]) * sc + bv[oc];
            O[pp * 132 + oc] = fmaxf(y, 0.f);
        }
        __syncthreads();
        const int o  = t * 4;                  // 0..2047
        const int qp = o >> 7, qc = o & 127;
        f32x4 yv = *(f32x4*)&O[qp * 132 + qc];
        f32x4 rv = *(const f32x4*)&xTf[(pix0 + qp) * 128 + qc];
        yv += rv;
        *(f32x4*)&outTf[(pix0 + qp) * 128 + qc] = yv;
        uint2 pk;
        pk.x = pack2(yv[0], yv[1]);
        pk.y = pack2(yv[2], yv[3]);
        *(uint2*)&outTb[(pix0 + qp) * 128 + qc] = pk;
    }
}

extern "C" void kernel_launch(void* const* d_in, const int* in_sizes, int n_in,
                              void* d_out, int out_size, void* d_ws, size_t ws_size,
                              hipStream_t stream) {
    (void)in_sizes; (void)n_in; (void)out_size; (void)ws_size;

    const float* hu = (const float*)d_in[0];

    short* wbs  = (short*)d_ws;                          // 3 * 147456 shorts
    short* owbs = wbs + 3 * Cn * KCn;                    // 3 * 36864 shorts
    unsigned short* T0b = (unsigned short*)(owbs + 3 * 32 * KCn);  // Bn*CHWn
    unsigned short* T1b = T0b + Bn * CHWn;
    float* T0f = (float*)(T1b + Bn * CHWn);
    float* T1f = T0f + Bn * CHWn;

    for (int i = 0; i < 3; ++i) {
        cvt_w_shuf<<<(Cn * KCn + 255) / 256, 256, 0, stream>>>(
            (const float*)d_in[3 + 7 * i], wbs + i * Cn * KCn);
        cvt_ow_shuf<<<(32 * KCn + 255) / 256, 256, 0, stream>>>(
            (const float*)d_in[1 + 7 * i], owbs + i * 32 * KCn);
    }

    nchw2nhwc<<<(Bn * HWn) / 64, 256, 0, stream>>>(hu, T0f, T0b);

    const int dils[3] = {2, 4, 8};
    const unsigned short* insb[3] = {T0b, T1b, T0b};
    const float*          insf[3] = {T0f, T1f, T0f};
    float*          outsf[3] = {T1f, T0f, nullptr};
    unsigned short* outsb[3] = {T1b, T0b, nullptr};
    const int nblk = (Bn * HWn) / 16;             // 1152

    for (int i = 0; i < 3; ++i) {
        const float* obv = (const float*)d_in[2 + 7 * i];
        const float* gv  = (const float*)d_in[4 + 7 * i];
        const float* bv  = (const float*)d_in[5 + 7 * i];
        const float* mv  = (const float*)d_in[6 + 7 * i];
        const float* vv  = (const float*)d_in[7 + 7 * i];
        const int last = (i == 2);

        fused_stage<<<nblk, 512, 0, stream>>>(
            insb[i], insf[i], wbs + i * Cn * KCn, owbs + i * 32 * KCn, obv,
            gv, bv, mv, vv, outsf[i], outsb[i],
            last ? (float*)d_out : nullptr, dils[i], last);
    }
}